// Round 6
// baseline (64.627 us; speedup 1.0000x reference)
//
#include <hip/hip_runtime.h>
#include <math.h>

#define B_    48
#define N_    512
#define NBOND 4096
#define H_    8
#define L_    2
#define G_    8                       // blocks per batch
#define TPB   512
#define BPB   (NBOND / G_)            // 512 bonds per block (1/thread)

#define LOG2E 1.44269504f

__device__ __forceinline__ float rcpf(float x)  { return __builtin_amdgcn_rcpf(x); }
__device__ __forceinline__ float exp2g(float x) { return __builtin_amdgcn_exp2f(x); }
__device__ __forceinline__ float log2g(float x) { return __builtin_amdgcn_logf(x); }
__device__ __forceinline__ float expg(float x)  { return exp2g(x * LOG2E); }
__device__ __forceinline__ float sigf(float x)  { return rcpf(1.0f + expg(-x)); }

__device__ __forceinline__ float taperf(float r) {
    const float rmin = 0.001f, rmax = 0.002f;
    const float d = rmin - rmax;
    const float rterm = 1.0f / (d * d * d);
    float r3  = (r > rmax) ? 1.0f : 0.0f;
    bool ok   = (r <= rmax) && (r > rmin);
    float r2  = ok ? r : 0.0f;
    float r20 = ok ? 1.0f : 0.0f;
    float rm   = rmin * r20;
    float rd   = rm - r2;
    float trm1 = rm + 2.0f * r2 - 3.0f * rmax * r20;
    return rterm * rd * rd * trm1 + r3;
}

// weights LDS layout
#define WI_OFF   0            // 3*3*8   = 72
#define W_OFF    72           // 3*2*8*8 = 384
#define BV_OFF   456          // 3*2*8   = 48
#define WO_OFF   504          // 3*8     = 24
#define BO_OFF   528          // 3
#define WTOT     531

__global__ __launch_bounds__(TPB) void fused_kernel(
    const float* __restrict__ x, const float* __restrict__ cell, const float* __restrict__ rcell,
    const int*  __restrict__ bdid, const int* __restrict__ atype,
    const float* __restrict__ rosi, const float* __restrict__ bo1, const float* __restrict__ bo2,
    const float* __restrict__ ropi, const float* __restrict__ bo3, const float* __restrict__ bo4,
    const float* __restrict__ ropp, const float* __restrict__ bo5, const float* __restrict__ bo6,
    const float* __restrict__ Desi,
    const float* __restrict__ sval, const float* __restrict__ svale, const float* __restrict__ slp2,
    const float* __restrict__ sov2, const float* __restrict__ sov5,
    const float* __restrict__ wi, const float* __restrict__ w, const float* __restrict__ bvec,
    const float* __restrict__ wo, const float* __restrict__ bo_out,
    int* __restrict__ ctr, float* __restrict__ pPart, float* __restrict__ pEbd,
    float* __restrict__ out)
{
    const int b   = blockIdx.x / G_;
    const int g   = blockIdx.x % G_;
    const int tid = threadIdx.x;

    __shared__ float sD[N_], sP[N_], sS[N_];
    __shared__ float sw[WTOT];
    __shared__ float sder[30];
    __shared__ float swave[TPB / 64];
    __shared__ int   sticket;

    if (tid < N_) { sD[tid] = 0.0f; sP[tid] = 0.0f; sS[tid] = 0.0f; }
    // TPB=512 < WTOT? no: 531 > 512, need strided loop
    for (int q = tid; q < WTOT; q += TPB) {
        float v;
        if      (q < W_OFF)  v = wi[q - WI_OFF];
        else if (q < BV_OFF) v = w[q - W_OFF];
        else if (q < WO_OFF) v = bvec[q - BV_OFF];
        else if (q < BO_OFF) v = wo[q - WO_OFF];
        else                 v = bo_out[q - BO_OFF];
        sw[q] = v;
    }
    if (tid < 3) {
        sder[tid * 10 + 0] = log2g(rosi[tid]);
        sder[tid * 10 + 1] = log2g(ropi[tid]);
        sder[tid * 10 + 2] = log2g(ropp[tid]);
        sder[tid * 10 + 3] = bo1[tid] * LOG2E;
        sder[tid * 10 + 4] = bo3[tid] * LOG2E;
        sder[tid * 10 + 5] = bo5[tid] * LOG2E;
        sder[tid * 10 + 6] = bo2[tid];
        sder[tid * 10 + 7] = bo4[tid];
        sder[tid * 10 + 8] = bo6[tid];
        sder[tid * 10 + 9] = Desi[tid];
    }
    float c00 = cell[0], c01 = cell[1], c02 = cell[2];
    float c10 = cell[3], c11 = cell[4], c12 = cell[5];
    float c20 = cell[6], c21 = cell[7], c22 = cell[8];
    float q00 = rcell[0], q01 = rcell[1], q02 = rcell[2];
    float q10 = rcell[3], q11 = rcell[4], q12 = rcell[5];
    float q20 = rcell[6], q21 = rcell[7], q22 = rcell[8];
    __syncthreads();

    const float* xb = x + (size_t)b * (N_ * 3);

    // ---- bond phase: 1 bond per thread ----
    int k = g * BPB + tid;
    int t = (k < 1600) ? 0 : ((k < 3200) ? 1 : 2);   // wave-uniform (boundaries are x64)
    const float* dc = sder + t * 10;

    int2 ij = ((const int2*)bdid)[k];
    int i = ij.x, j = ij.y;

    float vx = xb[3 * i + 0] - xb[3 * j + 0];
    float vy = xb[3 * i + 1] - xb[3 * j + 1];
    float vz = xb[3 * i + 2] - xb[3 * j + 2];

    float f0 = vx * q00 + vy * q10 + vz * q20;
    float f1 = vx * q01 + vy * q11 + vz * q21;
    float f2 = vx * q02 + vy * q12 + vz * q22;
    f0 = (f0 - 0.5f > 0.0f) ? f0 - 1.0f : f0;  f0 = (f0 + 0.5f < 0.0f) ? f0 + 1.0f : f0;
    f1 = (f1 - 0.5f > 0.0f) ? f1 - 1.0f : f1;  f1 = (f1 + 0.5f < 0.0f) ? f1 + 1.0f : f1;
    f2 = (f2 - 0.5f > 0.0f) ? f2 - 1.0f : f2;  f2 = (f2 + 0.5f < 0.0f) ? f2 + 1.0f : f2;
    float wx = f0 * c00 + f1 * c10 + f2 * c20;
    float wy = f0 * c01 + f1 * c11 + f2 * c21;
    float wz = f0 * c02 + f1 * c12 + f2 * c22;
    float r = __builtin_amdgcn_sqrtf(wx * wx + wy * wy + wz * wz);

    float lr = log2g(r);
    float p1 = exp2g(dc[6] * (lr - dc[0]));
    float p2 = exp2g(dc[7] * (lr - dc[1]));
    float p3 = exp2g(dc[8] * (lr - dc[2]));
    float e1 = 1.001f * exp2g(dc[3] * p1);
    float e2 = exp2g(dc[4] * p2);
    float e3 = exp2g(dc[5] * p3);
    float bosi = taperf(e1) * (e1 - 0.001f);
    float bopi = taperf(e2) * e2;
    float bopp = taperf(e3) * e3;

    const float* Wi = sw + WI_OFF + t * 24;
    const float* Wm = sw + W_OFF  + t * (L_ * H_ * H_);
    const float* Bv = sw + BV_OFF + t * (L_ * H_);
    const float* Wo = sw + WO_OFF + t * H_;
    float h[H_], h2[H_];
    #pragma unroll
    for (int hh = 0; hh < H_; ++hh) {
        float s = bosi * Wi[0 * H_ + hh] + bopi * Wi[1 * H_ + hh] + bopp * Wi[2 * H_ + hh];
        h[hh] = sigf(s);
    }
    #pragma unroll
    for (int l = 0; l < L_; ++l) {
        #pragma unroll
        for (int ho = 0; ho < H_; ++ho) {
            float s = Bv[l * H_ + ho];
            #pragma unroll
            for (int hi = 0; hi < H_; ++hi)
                s += h[hi] * Wm[l * (H_ * H_) + hi * H_ + ho];
            h2[ho] = sigf(s);
        }
        #pragma unroll
        for (int hh = 0; hh < H_; ++hh) h[hh] = h2[hh];
    }
    float o = sw[BO_OFF + t];
    #pragma unroll
    for (int hi = 0; hi < H_; ++hi) o += h[hi] * Wo[hi];
    float ebd = -dc[9] * sigf(o);

    float bo_sum = bosi + bopi + bopp;
    float bpi    = bopi + bopp;
    atomicAdd(&sD[i], bo_sum); atomicAdd(&sD[j], bo_sum);
    atomicAdd(&sP[i], bpi);    atomicAdd(&sP[j], bpi);
    atomicAdd(&sS[i], bosi);   atomicAdd(&sS[j], bosi);
    __syncthreads();

    // ---- write partials (non-atomic) + ebond partial ----
    float* pd = pPart + (size_t)(b * G_ + g) * (3 * N_);
    pd[tid]          = sD[tid];
    pd[N_ + tid]     = sP[tid];
    pd[2 * N_ + tid] = sS[tid];

    float v = ebd;
    for (int off = 32; off > 0; off >>= 1) v += __shfl_down(v, off, 64);
    int lane = tid & 63, wid = tid >> 6;
    if (lane == 0) swave[wid] = v;
    __syncthreads();   // also drains all global stores of this block
    if (tid == 0) {
        float s = 0.0f;
        #pragma unroll
        for (int wv = 0; wv < TPB / 64; ++wv) s += swave[wv];
        pEbd[b * G_ + g] = s;
        __threadfence();                       // device-scope release (writeback)
        sticket = atomicAdd(&ctr[b], 1);
    }
    __syncthreads();
    if (sticket != G_ - 1) return;

    // ---- merge block: atom pass for batch b ----
    __threadfence();                           // device-scope acquire (invalidate)

    float D = 0.0f, DP = 0.0f, so = 0.0f;
    #pragma unroll
    for (int gg = 0; gg < G_; ++gg) {
        const float* pp = pPart + (size_t)(b * G_ + gg) * (3 * N_);
        D  += pp[tid];
        DP += pp[N_ + tid];
        so += pp[2 * N_ + tid];
    }

    int at = atype[tid];
    float val  = sval[at];
    float vale = svale[at];
    float lp2  = slp2[at];
    float ov2  = sov2[at];
    float ov5  = sov5[at];

    float Nlp = 0.5f * (vale - val);
    float de  = 0.5f * (D - vale);
    float De  = fminf(ceilf(de), 0.0f);
    float t1  = 1.0f + de - De;
    float nlp = -De + expg(-40.0f * t1 * t1);
    float Dlp = fmaxf(Nlp - nlp + 1.0f, 0.0f) - 1.0f;
    float Elone = lp2 * Dlp * rcpf(1.0f + expg(-75.0f * Dlp));

    float dlc = D - val - Dlp * rcpf(1.0f + 5.0f * expg(3.0f * DP));
    float denom = dlc + val;
    float ot = rcpf((denom != 0.0f) ? denom : 1e-8f);
    float Eover = so * ot * dlc * sigf(-ov2 * dlc);

    float expeu1 = expg(6.0f * dlc);
    float eu1 = sigf(ov2 * dlc);
    float eu2 = rcpf(1.0f + expg(12.0f * DP));
    float Eunder = -ov5 * (1.0f - expeu1) * eu1 * eu2;

    float e = Elone + Eover + Eunder;
    if (tid < G_) e += pEbd[b * G_ + tid];

    float v2 = e;
    for (int off = 32; off > 0; off >>= 1) v2 += __shfl_down(v2, off, 64);
    if (lane == 0) swave[wid] = v2;
    __syncthreads();
    if (tid == 0) {
        float s = 0.0f;
        #pragma unroll
        for (int wv = 0; wv < TPB / 64; ++wv) s += swave[wv];
        out[b] = s;
    }
}

extern "C" void kernel_launch(void* const* d_in, const int* in_sizes, int n_in,
                              void* d_out, int out_size, void* d_ws, size_t ws_size,
                              hipStream_t stream)
{
    const float* x     = (const float*)d_in[0];
    const float* cell  = (const float*)d_in[1];
    const float* rcell = (const float*)d_in[2];
    const int*   bdid  = (const int*)d_in[3];
    const int*   atype = (const int*)d_in[4];
    const float* rosi  = (const float*)d_in[5];
    const float* bo1   = (const float*)d_in[6];
    const float* bo2   = (const float*)d_in[7];
    const float* ropi  = (const float*)d_in[8];
    const float* bo3   = (const float*)d_in[9];
    const float* bo4   = (const float*)d_in[10];
    const float* ropp  = (const float*)d_in[11];
    const float* bo5   = (const float*)d_in[12];
    const float* bo6   = (const float*)d_in[13];
    const float* Desi  = (const float*)d_in[14];
    const float* sval  = (const float*)d_in[15];
    const float* svale = (const float*)d_in[16];
    const float* slp2  = (const float*)d_in[17];
    const float* sov2  = (const float*)d_in[18];
    const float* sov5  = (const float*)d_in[19];
    const float* wi    = (const float*)d_in[20];
    const float* w     = (const float*)d_in[21];
    const float* bvec  = (const float*)d_in[22];
    const float* wo    = (const float*)d_in[23];
    const float* bo_o  = (const float*)d_in[24];
    float* out = (float*)d_out;

    int*   ctr   = (int*)d_ws;                                   // B_ ints (pad 64)
    float* pPart = (float*)d_ws + 64;                            // B*G*3*N floats
    float* pEbd  = pPart + (size_t)B_ * G_ * 3 * N_;             // B*G floats

    hipMemsetAsync(ctr, 0, 64 * sizeof(int), stream);

    fused_kernel<<<B_ * G_, TPB, 0, stream>>>(
        x, cell, rcell, bdid, atype,
        rosi, bo1, bo2, ropi, bo3, bo4, ropp, bo5, bo6, Desi,
        sval, svale, slp2, sov2, sov5,
        wi, w, bvec, wo, bo_o,
        ctr, pPart, pEbd, out);
}

// Round 7
// 21.378 us; speedup vs baseline: 3.0231x; 3.0231x over previous
//
#include <hip/hip_runtime.h>
#include <math.h>

#define B_    48
#define N_    512
#define NBOND 4096
#define H_    8
#define L_    2
#define G_    8                       // blocks per batch in bond pass
#define TPB1  512                     // 1 bond per thread
#define BPB   (NBOND / G_)            // 512 bonds per block
#define TPB2  512

#define LOG2E 1.44269504f

__device__ __forceinline__ float rcpf(float x)  { return __builtin_amdgcn_rcpf(x); }
__device__ __forceinline__ float exp2g(float x) { return __builtin_amdgcn_exp2f(x); }
__device__ __forceinline__ float log2g(float x) { return __builtin_amdgcn_logf(x); }
__device__ __forceinline__ float expg(float x)  { return exp2g(x * LOG2E); }
__device__ __forceinline__ float sigf(float x)  { return rcpf(1.0f + expg(-x)); }

__device__ __forceinline__ float taperf(float r) {
    const float rmin = 0.001f, rmax = 0.002f;
    const float d = rmin - rmax;
    const float rterm = 1.0f / (d * d * d);
    float r3  = (r > rmax) ? 1.0f : 0.0f;
    bool ok   = (r <= rmax) && (r > rmin);
    float r2  = ok ? r : 0.0f;
    float r20 = ok ? 1.0f : 0.0f;
    float rm   = rmin * r20;
    float rd   = rm - r2;
    float trm1 = rm + 2.0f * r2 - 3.0f * rmax * r20;
    return rterm * rd * rd * trm1 + r3;
}

// weights LDS layout
#define WI_OFF   0            // 3*3*8   = 72
#define W_OFF    72           // 3*2*8*8 = 384
#define BV_OFF   456          // 3*2*8   = 48
#define WO_OFF   504          // 3*8     = 24
#define BO_OFF   528          // 3
#define WTOT     531

__global__ __launch_bounds__(TPB1) void bond_kernel(
    const float* __restrict__ x, const float* __restrict__ cell, const float* __restrict__ rcell,
    const int*  __restrict__ bdid,
    const float* __restrict__ rosi, const float* __restrict__ bo1, const float* __restrict__ bo2,
    const float* __restrict__ ropi, const float* __restrict__ bo3, const float* __restrict__ bo4,
    const float* __restrict__ ropp, const float* __restrict__ bo5, const float* __restrict__ bo6,
    const float* __restrict__ Desi,
    const float* __restrict__ wi, const float* __restrict__ w, const float* __restrict__ bvec,
    const float* __restrict__ wo, const float* __restrict__ bo_out,
    float* __restrict__ pPart, float* __restrict__ pEbd)
{
    const int b   = blockIdx.x / G_;
    const int g   = blockIdx.x % G_;
    const int tid = threadIdx.x;

    __shared__ float sD[N_], sP[N_], sS[N_];
    __shared__ float sw[WTOT];
    __shared__ float sder[30];
    __shared__ float swave[TPB1 / 64];

    if (tid < N_) { sD[tid] = 0.0f; sP[tid] = 0.0f; sS[tid] = 0.0f; }
    for (int q = tid; q < WTOT; q += TPB1) {
        float v;
        if      (q < W_OFF)  v = wi[q - WI_OFF];
        else if (q < BV_OFF) v = w[q - W_OFF];
        else if (q < WO_OFF) v = bvec[q - BV_OFF];
        else if (q < BO_OFF) v = wo[q - WO_OFF];
        else                 v = bo_out[q - BO_OFF];
        sw[q] = v;
    }
    if (tid < 3) {
        sder[tid * 10 + 0] = log2g(rosi[tid]);
        sder[tid * 10 + 1] = log2g(ropi[tid]);
        sder[tid * 10 + 2] = log2g(ropp[tid]);
        sder[tid * 10 + 3] = bo1[tid] * LOG2E;
        sder[tid * 10 + 4] = bo3[tid] * LOG2E;
        sder[tid * 10 + 5] = bo5[tid] * LOG2E;
        sder[tid * 10 + 6] = bo2[tid];
        sder[tid * 10 + 7] = bo4[tid];
        sder[tid * 10 + 8] = bo6[tid];
        sder[tid * 10 + 9] = Desi[tid];
    }
    float c00 = cell[0], c01 = cell[1], c02 = cell[2];
    float c10 = cell[3], c11 = cell[4], c12 = cell[5];
    float c20 = cell[6], c21 = cell[7], c22 = cell[8];
    float q00 = rcell[0], q01 = rcell[1], q02 = rcell[2];
    float q10 = rcell[3], q11 = rcell[4], q12 = rcell[5];
    float q20 = rcell[6], q21 = rcell[7], q22 = rcell[8];
    __syncthreads();

    const float* xb = x + (size_t)b * (N_ * 3);

    // ---- bond phase: 1 bond per thread ----
    int k = g * BPB + tid;
    int t = (k < 1600) ? 0 : ((k < 3200) ? 1 : 2);   // wave-uniform (boundaries are x64)
    const float* dc = sder + t * 10;

    int2 ij = ((const int2*)bdid)[k];
    int i = ij.x, j = ij.y;

    float vx = xb[3 * i + 0] - xb[3 * j + 0];
    float vy = xb[3 * i + 1] - xb[3 * j + 1];
    float vz = xb[3 * i + 2] - xb[3 * j + 2];

    float f0 = vx * q00 + vy * q10 + vz * q20;
    float f1 = vx * q01 + vy * q11 + vz * q21;
    float f2 = vx * q02 + vy * q12 + vz * q22;
    f0 = (f0 - 0.5f > 0.0f) ? f0 - 1.0f : f0;  f0 = (f0 + 0.5f < 0.0f) ? f0 + 1.0f : f0;
    f1 = (f1 - 0.5f > 0.0f) ? f1 - 1.0f : f1;  f1 = (f1 + 0.5f < 0.0f) ? f1 + 1.0f : f1;
    f2 = (f2 - 0.5f > 0.0f) ? f2 - 1.0f : f2;  f2 = (f2 + 0.5f < 0.0f) ? f2 + 1.0f : f2;
    float wx = f0 * c00 + f1 * c10 + f2 * c20;
    float wy = f0 * c01 + f1 * c11 + f2 * c21;
    float wz = f0 * c02 + f1 * c12 + f2 * c22;
    float r = __builtin_amdgcn_sqrtf(wx * wx + wy * wy + wz * wz);

    float lr = log2g(r);
    float p1 = exp2g(dc[6] * (lr - dc[0]));
    float p2 = exp2g(dc[7] * (lr - dc[1]));
    float p3 = exp2g(dc[8] * (lr - dc[2]));
    float e1 = 1.001f * exp2g(dc[3] * p1);
    float e2 = exp2g(dc[4] * p2);
    float e3 = exp2g(dc[5] * p3);
    float bosi = taperf(e1) * (e1 - 0.001f);
    float bopi = taperf(e2) * e2;
    float bopp = taperf(e3) * e3;

    const float* Wi = sw + WI_OFF + t * 24;
    const float* Wm = sw + W_OFF  + t * (L_ * H_ * H_);
    const float* Bv = sw + BV_OFF + t * (L_ * H_);
    const float* Wo = sw + WO_OFF + t * H_;
    float h[H_], h2[H_];
    #pragma unroll
    for (int hh = 0; hh < H_; ++hh) {
        float s = bosi * Wi[0 * H_ + hh] + bopi * Wi[1 * H_ + hh] + bopp * Wi[2 * H_ + hh];
        h[hh] = sigf(s);
    }
    #pragma unroll
    for (int l = 0; l < L_; ++l) {
        #pragma unroll
        for (int ho = 0; ho < H_; ++ho) {
            float s = Bv[l * H_ + ho];
            #pragma unroll
            for (int hi = 0; hi < H_; ++hi)
                s += h[hi] * Wm[l * (H_ * H_) + hi * H_ + ho];
            h2[ho] = sigf(s);
        }
        #pragma unroll
        for (int hh = 0; hh < H_; ++hh) h[hh] = h2[hh];
    }
    float o = sw[BO_OFF + t];
    #pragma unroll
    for (int hi = 0; hi < H_; ++hi) o += h[hi] * Wo[hi];
    float ebd = -dc[9] * sigf(o);

    float bo_sum = bosi + bopi + bopp;
    float bpi    = bopi + bopp;
    atomicAdd(&sD[i], bo_sum); atomicAdd(&sD[j], bo_sum);
    atomicAdd(&sP[i], bpi);    atomicAdd(&sP[j], bpi);
    atomicAdd(&sS[i], bosi);   atomicAdd(&sS[j], bosi);
    __syncthreads();

    // ---- non-atomic partial writes: slice (b*G+g) ----
    float* pd = pPart + (size_t)(b * G_ + g) * (3 * N_);
    pd[tid]          = sD[tid];
    pd[N_ + tid]     = sP[tid];
    pd[2 * N_ + tid] = sS[tid];

    // block reduce ebond partial
    float v = ebd;
    for (int off = 32; off > 0; off >>= 1) v += __shfl_down(v, off, 64);
    int lane = tid & 63, wid = tid >> 6;
    if (lane == 0) swave[wid] = v;
    __syncthreads();
    if (tid == 0) {
        float s = 0.0f;
        #pragma unroll
        for (int wv = 0; wv < TPB1 / 64; ++wv) s += swave[wv];
        pEbd[b * G_ + g] = s;
    }
}

__global__ __launch_bounds__(TPB2) void atom_kernel(
    const int* __restrict__ atype,
    const float* __restrict__ sval, const float* __restrict__ svale, const float* __restrict__ slp2,
    const float* __restrict__ sov2, const float* __restrict__ sov5,
    const float* __restrict__ pPart, const float* __restrict__ pEbd,
    float* __restrict__ out)
{
    const int b   = blockIdx.x;
    const int tid = threadIdx.x;
    __shared__ float swave[TPB2 / 64];

    float D = 0.0f, DP = 0.0f, so = 0.0f;
    #pragma unroll
    for (int g = 0; g < G_; ++g) {
        const float* pd = pPart + (size_t)(b * G_ + g) * (3 * N_);
        D  += pd[tid];
        DP += pd[N_ + tid];
        so += pd[2 * N_ + tid];
    }

    int at = atype[tid];
    float val  = sval[at];
    float vale = svale[at];
    float lp2  = slp2[at];
    float ov2  = sov2[at];
    float ov5  = sov5[at];

    float Nlp = 0.5f * (vale - val);
    float de  = 0.5f * (D - vale);
    float De  = fminf(ceilf(de), 0.0f);
    float t1  = 1.0f + de - De;
    float nlp = -De + expg(-40.0f * t1 * t1);
    float Dlp = fmaxf(Nlp - nlp + 1.0f, 0.0f) - 1.0f;
    float Elone = lp2 * Dlp * rcpf(1.0f + expg(-75.0f * Dlp));

    float dlc = D - val - Dlp * rcpf(1.0f + 5.0f * expg(3.0f * DP));
    float denom = dlc + val;
    float ot = rcpf((denom != 0.0f) ? denom : 1e-8f);
    float Eover = so * ot * dlc * sigf(-ov2 * dlc);

    float expeu1 = expg(6.0f * dlc);
    float eu1 = sigf(ov2 * dlc);
    float eu2 = rcpf(1.0f + expg(12.0f * DP));
    float Eunder = -ov5 * (1.0f - expeu1) * eu1 * eu2;

    float e = Elone + Eover + Eunder;
    if (tid < G_) e += pEbd[b * G_ + tid];

    float v = e;
    for (int off = 32; off > 0; off >>= 1) v += __shfl_down(v, off, 64);
    int lane = tid & 63, wid = tid >> 6;
    if (lane == 0) swave[wid] = v;
    __syncthreads();
    if (tid == 0) {
        float s = 0.0f;
        #pragma unroll
        for (int wv = 0; wv < TPB2 / 64; ++wv) s += swave[wv];
        out[b] = s;
    }
}

extern "C" void kernel_launch(void* const* d_in, const int* in_sizes, int n_in,
                              void* d_out, int out_size, void* d_ws, size_t ws_size,
                              hipStream_t stream)
{
    const float* x     = (const float*)d_in[0];
    const float* cell  = (const float*)d_in[1];
    const float* rcell = (const float*)d_in[2];
    const int*   bdid  = (const int*)d_in[3];
    const int*   atype = (const int*)d_in[4];
    const float* rosi  = (const float*)d_in[5];
    const float* bo1   = (const float*)d_in[6];
    const float* bo2   = (const float*)d_in[7];
    const float* ropi  = (const float*)d_in[8];
    const float* bo3   = (const float*)d_in[9];
    const float* bo4   = (const float*)d_in[10];
    const float* ropp  = (const float*)d_in[11];
    const float* bo5   = (const float*)d_in[12];
    const float* bo6   = (const float*)d_in[13];
    const float* Desi  = (const float*)d_in[14];
    const float* sval  = (const float*)d_in[15];
    const float* svale = (const float*)d_in[16];
    const float* slp2  = (const float*)d_in[17];
    const float* sov2  = (const float*)d_in[18];
    const float* sov5  = (const float*)d_in[19];
    const float* wi    = (const float*)d_in[20];
    const float* w     = (const float*)d_in[21];
    const float* bvec  = (const float*)d_in[22];
    const float* wo    = (const float*)d_in[23];
    const float* bo_o  = (const float*)d_in[24];
    float* out = (float*)d_out;

    float* pPart = (float*)d_ws;                          // B*G*3*N floats
    float* pEbd  = pPart + (size_t)B_ * G_ * 3 * N_;      // B*G floats

    bond_kernel<<<B_ * G_, TPB1, 0, stream>>>(
        x, cell, rcell, bdid,
        rosi, bo1, bo2, ropi, bo3, bo4, ropp, bo5, bo6, Desi,
        wi, w, bvec, wo, bo_o,
        pPart, pEbd);

    atom_kernel<<<B_, TPB2, 0, stream>>>(
        atype, sval, svale, slp2, sov2, sov5,
        pPart, pEbd, out);
}